// Round 21
// baseline (62.532 us; speedup 1.0000x reference)
//
#include <hip/hip_runtime.h>
#include <hip/hip_bf16.h>
#include <math.h>

constexpr int NP  = 6144;   // rows
constexpr int DM  = 256;    // d_model
constexpr int DFF = 1024;   // ff dim
constexpr float LNEPS = 1e-5f;

typedef __attribute__((ext_vector_type(8))) short short8;
typedef __attribute__((ext_vector_type(4))) short short4v;
typedef __attribute__((ext_vector_type(4))) float f32x4;

__device__ __forceinline__ short f2bf(float f) {
    unsigned u = __builtin_bit_cast(unsigned, f);
    unsigned r = u + 0x7FFFu + ((u >> 16) & 1u);   // RNE
    return (short)(r >> 16);
}
__device__ __forceinline__ float bf2f(short s) {
    unsigned u = ((unsigned)(unsigned short)s) << 16;
    return __builtin_bit_cast(float, u);
}

// global->LDS direct 16B copy. LDS dest = wave-uniform base + lane*16;
// per-lane global src carries the swizzle (guide rule #21).
#define GLOAD16(gp, lp)                                                        \
    __builtin_amdgcn_global_load_lds(                                          \
        (const __attribute__((address_space(1))) unsigned int*)(gp),           \
        (__attribute__((address_space(3))) unsigned int*)(lp), 16, 0, 0)

// LDS tile [rows][64] shorts; chunk c of row r at slot c^(r&7).
__device__ __forceinline__ int lds_idx(int row, int chunk) {
    return row * 64 + ((chunk ^ (row & 7)) * 8);
}
// LDS tile [rows][128] shorts (BK=128); 16 chunks/row, same XOR rule.
__device__ __forceinline__ int lds_idx128(int row, int chunk) {
    return row * 128 + ((chunk ^ (row & 7)) * 8);
}

// ---------------------------------------------------------------------------
// prep: blocks 0..767 transpose+convert weights fp32[K][N] -> bf16[N][K];
// blocks 768..791 segment bounds; blocks 792..1559 convert x -> bf16.
// ---------------------------------------------------------------------------
__global__ __launch_bounds__(256) void prep_kernel(
    const float* __restrict__ qkv_w, const float* __restrict__ out_w,
    const float* __restrict__ ff_w1, const float* __restrict__ ff_w2,
    short* __restrict__ qkvT, short* __restrict__ outT,
    short* __restrict__ ff1T, short* __restrict__ ff2T,
    const int* __restrict__ dom, int* __restrict__ seg_s,
    int* __restrict__ seg_e, const float* __restrict__ x,
    short* __restrict__ xB) {
    int b = blockIdx.x;
    if (b >= 792) {   // x -> bf16
        int i = (b - 792) * 2048 + threadIdx.x * 8;
        float4 a0 = *(const float4*)&x[i];
        float4 a1 = *(const float4*)&x[i + 4];
        short8 v = { f2bf(a0.x), f2bf(a0.y), f2bf(a0.z), f2bf(a0.w),
                     f2bf(a1.x), f2bf(a1.y), f2bf(a1.z), f2bf(a1.w) };
        *(short8*)&xB[i] = v;
        return;
    }
    if (b >= 768) {   // segment bounds
        int i = (b - 768) * 256 + threadIdx.x;
        if (i >= NP) return;
        int d = dom[i];
        int s = i;
        while (s > 0 && dom[s - 1] == d) --s;
        int e = i + 1;
        while (e < NP && dom[e] == d) ++e;
        seg_s[i] = s;
        seg_e[i] = e;
        return;
    }
    const float* src;
    short* dst;
    int K, Nn;
    if (b < 192)      { src = qkv_w; dst = qkvT; K = 256;  Nn = 768; }
    else if (b < 256) { b -= 192; src = out_w; dst = outT; K = 256;  Nn = 256; }
    else if (b < 512) { b -= 256; src = ff_w1; dst = ff1T; K = 256;  Nn = 1024; }
    else              { b -= 512; src = ff_w2; dst = ff2T; K = 1024; Nn = 256; }
    int tpr = Nn / 32;
    int k0 = (b / tpr) * 32, n0 = (b % tpr) * 32;

    __shared__ float lds[32][36];
    int t = threadIdx.x;
    {
        int k = t >> 3, n = (t & 7) * 4;
        *(float4*)&lds[k][n] = *(const float4*)&src[(size_t)(k0 + k) * Nn + n0 + n];
    }
    __syncthreads();
    {
        int n = t >> 3, ks = (t & 7) * 4;
        short4v o = { f2bf(lds[ks + 0][n]), f2bf(lds[ks + 1][n]),
                      f2bf(lds[ks + 2][n]), f2bf(lds[ks + 3][n]) };
        *(short4v*)&dst[(size_t)(n0 + n) * K + k0 + ks] = o;
    }
}

// ---------------------------------------------------------------------------
// mgemm128x64: 128x64 tiles, BK=128. Wave owns 64x32 (4x2 frags).
// XCD-aware bijective swizzle. EPI: 0 bf16; 1 gelu bf16.
// ---------------------------------------------------------------------------
template <int EPI>
__global__ __launch_bounds__(256) void mgemm128x64(
    const short* __restrict__ A, const short* __restrict__ Bt,
    const float* __restrict__ bias, short* __restrict__ C, int Nn, int K) {
    __shared__ __align__(16) short As[128 * 128];  // 32 KB
    __shared__ __align__(16) short Bs[64 * 128];   // 16 KB

    const int tid = threadIdx.x, lane = tid & 63, w = tid >> 6;
    const int wm = (w >> 1) * 64, wn = (w & 1) * 32;

    const int nx = gridDim.x;
    const int bid = blockIdx.y * nx + blockIdx.x;
    const int q = (nx * gridDim.y) >> 3;
    const int id2 = (bid & 7) * q + (bid >> 3);
    const int rowBase = (id2 / nx) * 128, colBase = (id2 % nx) * 64;

    const int lr4 = lane >> 4;            // row-in-4 for BK=128 staging
    const int c16 = lane & 15;            // dest chunk 0..15
    const int fr = lane & 15, g4 = lane >> 4;

    f32x4 acc[4][2];
#pragma unroll
    for (int i = 0; i < 4; ++i)
#pragma unroll
        for (int j = 0; j < 2; ++j) acc[i][j] = f32x4{0.f, 0.f, 0.f, 0.f};

    for (int k0 = 0; k0 < K; k0 += 128) {
#pragma unroll
        for (int i = 0; i < 12; ++i) {            // 48 groups: A 32, B 16
            int g = w * 12 + i;
            if (g < 32) {
                int row = g * 4 + lr4;
                int sc = c16 ^ (row & 7);
                GLOAD16(A + (size_t)(rowBase + row) * K + k0 + sc * 8, &As[g * 512]);
            } else {
                int row = (g - 32) * 4 + lr4;
                int sc = c16 ^ (row & 7);
                GLOAD16(Bt + (size_t)(colBase + row) * K + k0 + sc * 8,
                        &Bs[(g - 32) * 512]);
            }
        }
        __syncthreads();

#pragma unroll
        for (int kk = 0; kk < 4; ++kk) {
            int j = kk * 4 + g4;                  // chunk 0..15
            short8 af[4], bfv[2];
#pragma unroll
            for (int f = 0; f < 4; ++f)
                af[f] = *(const short8*)&As[lds_idx128(wm + f * 16 + fr, j)];
#pragma unroll
            for (int f = 0; f < 2; ++f)
                bfv[f] = *(const short8*)&Bs[lds_idx128(wn + f * 16 + fr, j)];
#pragma unroll
            for (int fm = 0; fm < 4; ++fm)
#pragma unroll
                for (int fn = 0; fn < 2; ++fn)
                    acc[fm][fn] = __builtin_amdgcn_mfma_f32_16x16x32_bf16(
                        af[fm], bfv[fn], acc[fm][fn], 0, 0, 0);
        }
        __syncthreads();
    }

    const int cr = g4 * 4;
#pragma unroll
    for (int fm = 0; fm < 4; ++fm)
#pragma unroll
        for (int fn = 0; fn < 2; ++fn) {
            int c = colBase + wn + fn * 16 + fr;
            float bv = bias[c];
#pragma unroll
            for (int j = 0; j < 4; ++j) {
                int r = rowBase + wm + fm * 16 + cr + j;
                float v = acc[fm][fn][j] + bv;
                if (EPI == 1) v = 0.5f * v * (1.0f + erff(v * 0.70710678118654752f));
                C[(size_t)r * Nn + c] = f2bf(v);
            }
        }
}

// ---------------------------------------------------------------------------
// gemmln32: fused out = LN2( hB @ ff2T^T + ff_b2 + x1 ), fp32 out.
// 32 rows/block -> 192 blocks x 512 threads (R18's gemmln16 failure root
// cause was 384 blocks x 512 KB B-restaging = 192 MB; at 32 rows B-traffic
// halves to 98 MB = the split version's). BK=128, 8 k-steps, LDS 74 KB ->
// 2 blocks/CU. XCD-chunked swizzle keeps each XCD's hB panel L2-local.
// ---------------------------------------------------------------------------
__global__ __launch_bounds__(512) void gemmln32(
    const short* __restrict__ A, const short* __restrict__ Bt,
    const float* __restrict__ bias, const short* __restrict__ res,
    const float* __restrict__ gw, const float* __restrict__ bw,
    float* __restrict__ out) {
    __shared__ __align__(16) short As[32 * 128];    // 8 KB
    __shared__ __align__(16) short Bs[256 * 128];   // 64 KB
    __shared__ float r1[8][32], r2[8][32];

    const int tid = threadIdx.x, lane = tid & 63, w = tid >> 6;
    // XCD-chunked swizzle: 192 blocks, q = 24 per XCD
    const int bid = blockIdx.x;
    const int q = gridDim.x >> 3;
    const int id2 = (bid & 7) * q + (bid >> 3);
    const int rowBase = id2 * 32;
    const int lr4 = lane >> 4, c16 = lane & 15;
    const int fr = lane & 15, g4 = lane >> 4;

    f32x4 acc[2][2];
#pragma unroll
    for (int i = 0; i < 2; ++i)
#pragma unroll
        for (int j = 0; j < 2; ++j) acc[i][j] = f32x4{0.f, 0.f, 0.f, 0.f};

    for (int k0 = 0; k0 < 1024; k0 += 128) {
        {   // A: 32 rows = 8 groups, one per wave
            int row = w * 4 + lr4;
            int sc = c16 ^ (row & 7);
            GLOAD16(A + (size_t)(rowBase + row) * 1024 + k0 + sc * 8, &As[w * 512]);
        }
#pragma unroll
        for (int i = 0; i < 8; ++i) {             // B: 256 rows = 64 groups
            int g = w * 8 + i;
            int row = g * 4 + lr4;
            int sc = c16 ^ (row & 7);
            GLOAD16(Bt + (size_t)row * 1024 + k0 + sc * 8, &Bs[g * 512]);
        }
        __syncthreads();
#pragma unroll
        for (int kk = 0; kk < 4; ++kk) {
            int j = kk * 4 + g4;
            short8 af[2], bfv[2];
#pragma unroll
            for (int fm = 0; fm < 2; ++fm)
                af[fm] = *(const short8*)&As[lds_idx128(fm * 16 + fr, j)];
#pragma unroll
            for (int fn = 0; fn < 2; ++fn)
                bfv[fn] = *(const short8*)&Bs[lds_idx128(w * 32 + fn * 16 + fr, j)];
#pragma unroll
            for (int fm = 0; fm < 2; ++fm)
#pragma unroll
                for (int fn = 0; fn < 2; ++fn)
                    acc[fm][fn] = __builtin_amdgcn_mfma_f32_16x16x32_bf16(
                        af[fm], bfv[fn], acc[fm][fn], 0, 0, 0);
        }
        __syncthreads();
    }

    // bias + residual(x1 bf16) + LN2 -> out fp32
    float v[2][2][4], p1[2][4], p2[2][4];
#pragma unroll
    for (int fm = 0; fm < 2; ++fm)
#pragma unroll
        for (int j = 0; j < 4; ++j) { p1[fm][j] = 0.f; p2[fm][j] = 0.f; }
#pragma unroll
    for (int fm = 0; fm < 2; ++fm)
#pragma unroll
        for (int fn = 0; fn < 2; ++fn) {
            int c = w * 32 + fn * 16 + fr;
            float bv = bias[c];
#pragma unroll
            for (int j = 0; j < 4; ++j) {
                int r = rowBase + fm * 16 + g4 * 4 + j;
                float t = acc[fm][fn][j] + bv + bf2f(res[(size_t)r * 256 + c]);
                v[fm][fn][j] = t;
                p1[fm][j] += t;
                p2[fm][j] += t * t;
            }
        }
#pragma unroll
    for (int m = 1; m < 16; m <<= 1)
#pragma unroll
        for (int fm = 0; fm < 2; ++fm)
#pragma unroll
            for (int j = 0; j < 4; ++j) {
                p1[fm][j] += __shfl_xor(p1[fm][j], m);
                p2[fm][j] += __shfl_xor(p2[fm][j], m);
            }
    if (fr == 0) {
#pragma unroll
        for (int fm = 0; fm < 2; ++fm)
#pragma unroll
            for (int j = 0; j < 4; ++j) {
                r1[w][fm * 16 + g4 * 4 + j] = p1[fm][j];
                r2[w][fm * 16 + g4 * 4 + j] = p2[fm][j];
            }
    }
    __syncthreads();
#pragma unroll
    for (int fm = 0; fm < 2; ++fm)
#pragma unroll
        for (int j = 0; j < 4; ++j) {
            int rl = fm * 16 + g4 * 4 + j;
            int r = rowBase + rl;
            float s1 = 0.f, s2 = 0.f;
#pragma unroll
            for (int ww = 0; ww < 8; ++ww) { s1 += r1[ww][rl]; s2 += r2[ww][rl]; }
            float mu = s1 * (1.0f / 256.0f);
            float var = s2 * (1.0f / 256.0f) - mu * mu;
            float rstd = rsqrtf(var + LNEPS);
#pragma unroll
            for (int fn = 0; fn < 2; ++fn) {
                int c = w * 32 + fn * 16 + fr;
                out[(size_t)r * 256 + c] = (v[fm][fn][j] - mu) * rstd * gw[c] + bw[c];
            }
        }
}

// ---------------------------------------------------------------------------
// attnln: fused {segment attention for 16 rows} + {out-proj GEMM, BK=128}
// + {residual + LN1} -> x1 bf16. 384 blocks x 512 threads. (R20 exact:
// XCD-chunked swizzle + bf16 residual.)
// ---------------------------------------------------------------------------
__global__ __launch_bounds__(512) void attnln_kernel(
    const short* __restrict__ qkvB, const int* __restrict__ seg_s,
    const int* __restrict__ seg_e, const short* __restrict__ outT,
    const float* __restrict__ out_b, const short* __restrict__ xres,
    const float* __restrict__ gw, const float* __restrict__ bw,
    short* __restrict__ x1) {
    __shared__ __align__(16) short As[16 * 256];    // attn out, swizzled, 8 KB
    __shared__ __align__(16) short Bs[256 * 128];   // 64 KB (BK=128)
    __shared__ float r1[8][16], r2[8][16];

    const int tid = threadIdx.x, lane = tid & 63, w = tid >> 6;
    const int bid = blockIdx.x;
    const int q = gridDim.x >> 3;
    const int id2 = (bid & 7) * q + (bid >> 3);
    const int rowBase = id2 * 16;
    const int lr4 = lane >> 4, c16 = lane & 15;
    const int fr = lane & 15, g4 = lane >> 4;

    // ---- attention (16 rows x 4 heads = 64 tasks, one per 8-lane group) ----
    {
        const int l8 = lane & 7;
        const int G  = (w << 3) | (lane >> 3);   // 0..63
        int r = G >> 2, h = G & 3;
        int row = rowBase + r;
        short8 qv = *(const short8*)&qkvB[(size_t)row * 768 + h * 64 + l8 * 8];
        float qd[8];
#pragma unroll
        for (int e = 0; e < 8; ++e) qd[e] = bf2f(qv[e]);
        int ss = seg_s[row], ee = seg_e[row];
        float m = -INFINITY, l = 0.0f;
        float acc[8] = {0.f, 0.f, 0.f, 0.f, 0.f, 0.f, 0.f, 0.f};
        for (int j = ss; j < ee; ++j) {
            short8 kv = *(const short8*)&qkvB[(size_t)j * 768 + 256 + h * 64 + l8 * 8];
            short8 vv = *(const short8*)&qkvB[(size_t)j * 768 + 512 + h * 64 + l8 * 8];
            float prod = 0.f;
#pragma unroll
            for (int e = 0; e < 8; ++e) prod += qd[e] * bf2f(kv[e]);
            prod += __shfl_xor(prod, 1);
            prod += __shfl_xor(prod, 2);
            prod += __shfl_xor(prod, 4);
            float score = prod * 0.125f;
            float mn = fmaxf(m, score);
            float scale = __expf(m - mn);
            float p = __expf(score - mn);
            l = l * scale + p;
#pragma unroll
            for (int e = 0; e < 8; ++e) acc[e] = acc[e] * scale + p * bf2f(vv[e]);
            m = mn;
        }
        float inv = 1.0f / l;
        int c = h * 8 + l8;
        short8 o;
#pragma unroll
        for (int e = 0; e < 8; ++e) o[e] = f2bf(acc[e] * inv);
        *(short8*)&As[r * 256 + ((c ^ (r & 7)) * 8)] = o;
    }
    __syncthreads();

    // ---- GEMM (A=attn LDS, B=outT staged BK=128) + residual + LN1 ----
    f32x4 acc[2];
    acc[0] = f32x4{0.f, 0.f, 0.f, 0.f};
    acc[1] = f32x4{0.f, 0.f, 0.f, 0.f};

    for (int k0 = 0; k0 < 256; k0 += 128) {
#pragma unroll
        for (int i = 0; i < 8; ++i) {             // 64 groups of 4 rows
            int g = w * 8 + i;
            int row = g * 4 + lr4;
            int sc = c16 ^ (row & 7);
            GLOAD16(outT + (size_t)row * 256 + k0 + sc * 8, &Bs[g * 512]);
        }
        __syncthreads();
#pragma unroll
        for (int kk = 0; kk < 4; ++kk) {
            int j = kk * 4 + g4;                  // chunk-in-kstep 0..15
            int cj = (k0 >> 3) + j;               // global chunk 0..31
            short8 af = *(const short8*)&As[fr * 256 + ((cj ^ (fr & 7)) * 8)];
            short8 bfv[2];
#pragma unroll
            for (int fn = 0; fn < 2; ++fn)
                bfv[fn] = *(const short8*)&Bs[lds_idx128(w * 32 + fn * 16 + fr, j)];
#pragma unroll
            for (int fn = 0; fn < 2; ++fn)
                acc[fn] = __builtin_amdgcn_mfma_f32_16x16x32_bf16(
                    af, bfv[fn], acc[fn], 0, 0, 0);
        }
        __syncthreads();
    }

    float v[2][4], p1[4], p2[4];
#pragma unroll
    for (int j = 0; j < 4; ++j) { p1[j] = 0.f; p2[j] = 0.f; }
#pragma unroll
    for (int fn = 0; fn < 2; ++fn) {
        int c = w * 32 + fn * 16 + fr;
        float bv = out_b[c];
#pragma unroll
        for (int j = 0; j < 4; ++j) {
            int r = rowBase + g4 * 4 + j;
            float t = acc[fn][j] + bv + bf2f(xres[(size_t)r * 256 + c]);
            v[fn][j] = t;
            p1[j] += t;
            p2[j] += t * t;
        }
    }
#pragma unroll
    for (int m = 1; m < 16; m <<= 1)
#pragma unroll
        for (int j = 0; j < 4; ++j) {
            p1[j] += __shfl_xor(p1[j], m);
            p2[j] += __shfl_xor(p2[j], m);
        }
    if (fr == 0) {
#pragma unroll
        for (int j = 0; j < 4; ++j) {
            r1[w][g4 * 4 + j] = p1[j];
            r2[w][g4 * 4 + j] = p2[j];
        }
    }
    __syncthreads();
#pragma unroll
    for (int j = 0; j < 4; ++j) {
        int rl = g4 * 4 + j;
        int r = rowBase + rl;
        float s1 = 0.f, s2 = 0.f;
#pragma unroll
        for (int ww = 0; ww < 8; ++ww) { s1 += r1[ww][rl]; s2 += r2[ww][rl]; }
        float mu = s1 * (1.0f / 256.0f);
        float var = s2 * (1.0f / 256.0f) - mu * mu;
        float rstd = rsqrtf(var + LNEPS);
#pragma unroll
        for (int fn = 0; fn < 2; ++fn) {
            int c = w * 32 + fn * 16 + fr;
            float o = (v[fn][j] - mu) * rstd * gw[c] + bw[c];
            x1[(size_t)r * 256 + c] = f2bf(o);
        }
    }
}

// ---------------------------------------------------------------------------
extern "C" void kernel_launch(void* const* d_in, const int* in_sizes, int n_in,
                              void* d_out, int out_size, void* d_ws, size_t ws_size,
                              hipStream_t stream) {
    const float* x      = (const float*)d_in[0];
    const int*   dom    = (const int*)d_in[1];
    const float* qkv_w  = (const float*)d_in[2];
    const float* qkv_b  = (const float*)d_in[3];
    const float* out_w  = (const float*)d_in[4];
    const float* out_b  = (const float*)d_in[5];
    const float* ff_w1  = (const float*)d_in[6];
    const float* ff_b1  = (const float*)d_in[7];
    const float* ff_w2  = (const float*)d_in[8];
    const float* ff_b2  = (const float*)d_in[9];
    const float* ln1_g  = (const float*)d_in[10];
    const float* ln1_b  = (const float*)d_in[11];
    const float* ln2_g  = (const float*)d_in[12];
    const float* ln2_b  = (const float*)d_in[13];
    float* out = (float*)d_out;

    short* xB     = (short*)d_ws;                    // NP x 256
    short* qkvB   = xB + (size_t)NP * 256;           // NP x 768
    short* x1     = qkvB + (size_t)NP * 768;         // NP x 256
    short* hB     = x1 + (size_t)NP * 256;           // NP x 1024
    short* qkvT   = hB + (size_t)NP * 1024;          // 768 x 256
    short* outT   = qkvT + 768 * 256;                // 256 x 256
    short* ff1T   = outT + 256 * 256;                // 1024 x 256
    short* ff2T   = ff1T + 1024 * 256;               // 256 x 1024
    int* seg_s    = (int*)(ff2T + 256 * 1024);
    int* seg_e    = seg_s + NP;

    // 0) weight transpose/convert + segment bounds + x->bf16
    prep_kernel<<<1560, 256, 0, stream>>>(qkv_w, out_w, ff_w1, ff_w2,
                                          qkvT, outT, ff1T, ff2T,
                                          dom, seg_s, seg_e, x, xB);

    // 1) qkv = x @ qkv_w + qkv_b                (bf16 out, 576 blocks)
    mgemm128x64<0><<<dim3(768 / 64, NP / 128), 256, 0, stream>>>(
        xB, qkvT, qkv_b, qkvB, 768, 256);

    // 2) x1 = LN1(x + attn(qkv) @ out_w + out_b)   (fused, 384 blocks)
    attnln_kernel<<<NP / 16, 512, 0, stream>>>(
        qkvB, seg_s, seg_e, outT, out_b, xB, ln1_g, ln1_b, x1);

    // 3) h = gelu(x1 @ ff_w1 + ff_b1)           (bf16 out, 768 blocks)
    mgemm128x64<1><<<dim3(DFF / 64, NP / 128), 256, 0, stream>>>(
        x1, ff1T, ff_b1, hB, 1024, 256);

    // 4) out = LN2(x1 + hB @ ff_w2 + ff_b2)     (fused, fp32 out, 192 blocks)
    gemmln32<<<NP / 32, 512, 0, stream>>>(
        hB, ff2T, ff_b2, x1, ln2_g, ln2_b, out);
}

// Round 22
// 58.410 us; speedup vs baseline: 1.0706x; 1.0706x over previous
//
#include <hip/hip_runtime.h>
#include <hip/hip_bf16.h>
#include <math.h>

constexpr int NP  = 6144;   // rows
constexpr int DM  = 256;    // d_model
constexpr int DFF = 1024;   // ff dim
constexpr float LNEPS = 1e-5f;

typedef __attribute__((ext_vector_type(8))) short short8;
typedef __attribute__((ext_vector_type(4))) short short4v;
typedef __attribute__((ext_vector_type(4))) float f32x4;

__device__ __forceinline__ short f2bf(float f) {
    unsigned u = __builtin_bit_cast(unsigned, f);
    unsigned r = u + 0x7FFFu + ((u >> 16) & 1u);   // RNE
    return (short)(r >> 16);
}
__device__ __forceinline__ float bf2f(short s) {
    unsigned u = ((unsigned)(unsigned short)s) << 16;
    return __builtin_bit_cast(float, u);
}

// global->LDS direct 16B copy. LDS dest = wave-uniform base + lane*16;
// per-lane global src carries the swizzle (guide rule #21).
#define GLOAD16(gp, lp)                                                        \
    __builtin_amdgcn_global_load_lds(                                          \
        (const __attribute__((address_space(1))) unsigned int*)(gp),           \
        (__attribute__((address_space(3))) unsigned int*)(lp), 16, 0, 0)

// LDS tile [rows][64] shorts; chunk c of row r at slot c^(r&7).
__device__ __forceinline__ int lds_idx(int row, int chunk) {
    return row * 64 + ((chunk ^ (row & 7)) * 8);
}
// LDS tile [rows][128] shorts (BK=128); 16 chunks/row, same XOR rule.
__device__ __forceinline__ int lds_idx128(int row, int chunk) {
    return row * 128 + ((chunk ^ (row & 7)) * 8);
}

// ---------------------------------------------------------------------------
// prep: blocks 0..767 transpose+convert weights fp32[K][N] -> bf16[N][K];
// blocks 768..791 segment bounds; blocks 792..1559 convert x -> bf16.
// ---------------------------------------------------------------------------
__global__ __launch_bounds__(256) void prep_kernel(
    const float* __restrict__ qkv_w, const float* __restrict__ out_w,
    const float* __restrict__ ff_w1, const float* __restrict__ ff_w2,
    short* __restrict__ qkvT, short* __restrict__ outT,
    short* __restrict__ ff1T, short* __restrict__ ff2T,
    const int* __restrict__ dom, int* __restrict__ seg_s,
    int* __restrict__ seg_e, const float* __restrict__ x,
    short* __restrict__ xB) {
    int b = blockIdx.x;
    if (b >= 792) {   // x -> bf16
        int i = (b - 792) * 2048 + threadIdx.x * 8;
        float4 a0 = *(const float4*)&x[i];
        float4 a1 = *(const float4*)&x[i + 4];
        short8 v = { f2bf(a0.x), f2bf(a0.y), f2bf(a0.z), f2bf(a0.w),
                     f2bf(a1.x), f2bf(a1.y), f2bf(a1.z), f2bf(a1.w) };
        *(short8*)&xB[i] = v;
        return;
    }
    if (b >= 768) {   // segment bounds
        int i = (b - 768) * 256 + threadIdx.x;
        if (i >= NP) return;
        int d = dom[i];
        int s = i;
        while (s > 0 && dom[s - 1] == d) --s;
        int e = i + 1;
        while (e < NP && dom[e] == d) ++e;
        seg_s[i] = s;
        seg_e[i] = e;
        return;
    }
    const float* src;
    short* dst;
    int K, Nn;
    if (b < 192)      { src = qkv_w; dst = qkvT; K = 256;  Nn = 768; }
    else if (b < 256) { b -= 192; src = out_w; dst = outT; K = 256;  Nn = 256; }
    else if (b < 512) { b -= 256; src = ff_w1; dst = ff1T; K = 256;  Nn = 1024; }
    else              { b -= 512; src = ff_w2; dst = ff2T; K = 1024; Nn = 256; }
    int tpr = Nn / 32;
    int k0 = (b / tpr) * 32, n0 = (b % tpr) * 32;

    __shared__ float lds[32][36];
    int t = threadIdx.x;
    {
        int k = t >> 3, n = (t & 7) * 4;
        *(float4*)&lds[k][n] = *(const float4*)&src[(size_t)(k0 + k) * Nn + n0 + n];
    }
    __syncthreads();
    {
        int n = t >> 3, ks = (t & 7) * 4;
        short4v o = { f2bf(lds[ks + 0][n]), f2bf(lds[ks + 1][n]),
                      f2bf(lds[ks + 2][n]), f2bf(lds[ks + 3][n]) };
        *(short4v*)&dst[(size_t)(n0 + n) * K + k0 + ks] = o;
    }
}

// ---------------------------------------------------------------------------
// mgemm128x64: 128x64 tiles, BK=128. Wave owns 64x32 (4x2 frags).
// XCD-aware bijective swizzle. EPI: 0 bf16; 1 gelu bf16.
// ---------------------------------------------------------------------------
template <int EPI>
__global__ __launch_bounds__(256) void mgemm128x64(
    const short* __restrict__ A, const short* __restrict__ Bt,
    const float* __restrict__ bias, short* __restrict__ C, int Nn, int K) {
    __shared__ __align__(16) short As[128 * 128];  // 32 KB
    __shared__ __align__(16) short Bs[64 * 128];   // 16 KB

    const int tid = threadIdx.x, lane = tid & 63, w = tid >> 6;
    const int wm = (w >> 1) * 64, wn = (w & 1) * 32;

    const int nx = gridDim.x;
    const int bid = blockIdx.y * nx + blockIdx.x;
    const int q = (nx * gridDim.y) >> 3;
    const int id2 = (bid & 7) * q + (bid >> 3);
    const int rowBase = (id2 / nx) * 128, colBase = (id2 % nx) * 64;

    const int lr4 = lane >> 4;            // row-in-4 for BK=128 staging
    const int c16 = lane & 15;            // dest chunk 0..15
    const int fr = lane & 15, g4 = lane >> 4;

    f32x4 acc[4][2];
#pragma unroll
    for (int i = 0; i < 4; ++i)
#pragma unroll
        for (int j = 0; j < 2; ++j) acc[i][j] = f32x4{0.f, 0.f, 0.f, 0.f};

    for (int k0 = 0; k0 < K; k0 += 128) {
#pragma unroll
        for (int i = 0; i < 12; ++i) {            // 48 groups: A 32, B 16
            int g = w * 12 + i;
            if (g < 32) {
                int row = g * 4 + lr4;
                int sc = c16 ^ (row & 7);
                GLOAD16(A + (size_t)(rowBase + row) * K + k0 + sc * 8, &As[g * 512]);
            } else {
                int row = (g - 32) * 4 + lr4;
                int sc = c16 ^ (row & 7);
                GLOAD16(Bt + (size_t)(colBase + row) * K + k0 + sc * 8,
                        &Bs[(g - 32) * 512]);
            }
        }
        __syncthreads();

#pragma unroll
        for (int kk = 0; kk < 4; ++kk) {
            int j = kk * 4 + g4;                  // chunk 0..15
            short8 af[4], bfv[2];
#pragma unroll
            for (int f = 0; f < 4; ++f)
                af[f] = *(const short8*)&As[lds_idx128(wm + f * 16 + fr, j)];
#pragma unroll
            for (int f = 0; f < 2; ++f)
                bfv[f] = *(const short8*)&Bs[lds_idx128(wn + f * 16 + fr, j)];
#pragma unroll
            for (int fm = 0; fm < 4; ++fm)
#pragma unroll
                for (int fn = 0; fn < 2; ++fn)
                    acc[fm][fn] = __builtin_amdgcn_mfma_f32_16x16x32_bf16(
                        af[fm], bfv[fn], acc[fm][fn], 0, 0, 0);
        }
        __syncthreads();
    }

    const int cr = g4 * 4;
#pragma unroll
    for (int fm = 0; fm < 4; ++fm)
#pragma unroll
        for (int fn = 0; fn < 2; ++fn) {
            int c = colBase + wn + fn * 16 + fr;
            float bv = bias[c];
#pragma unroll
            for (int j = 0; j < 4; ++j) {
                int r = rowBase + wm + fm * 16 + cr + j;
                float v = acc[fm][fn][j] + bv;
                if (EPI == 1) v = 0.5f * v * (1.0f + erff(v * 0.70710678118654752f));
                C[(size_t)r * Nn + c] = f2bf(v);
            }
        }
}

// ---------------------------------------------------------------------------
// mgemm64: 64x64 tiles, BK=128 (R16-proven). EPI 2: +res(bf16), bf16 y out.
// ---------------------------------------------------------------------------
template <int EPI>
__global__ __launch_bounds__(256) void mgemm64(
    const short* __restrict__ A, const short* __restrict__ Bt,
    const float* __restrict__ bias, const short* __restrict__ res,
    void* __restrict__ Cv, int Nn, int K) {
    __shared__ __align__(16) short As[64 * 128];   // 16 KB
    __shared__ __align__(16) short Bs[64 * 128];   // 16 KB

    const int tid = threadIdx.x, lane = tid & 63, w = tid >> 6;
    const int wm = (w >> 1) * 32, wn = (w & 1) * 32;

    const int nx = gridDim.x;
    const int bid = blockIdx.y * nx + blockIdx.x;
    const int q = (nx * gridDim.y) >> 3;
    const int id2 = (bid & 7) * q + (bid >> 3);
    const int rowBase = (id2 / nx) * 64, colBase = (id2 % nx) * 64;

    const int lr4 = lane >> 4;
    const int c16 = lane & 15;
    const int fr = lane & 15, g4 = lane >> 4;

    f32x4 acc[2][2];
#pragma unroll
    for (int i = 0; i < 2; ++i)
#pragma unroll
        for (int j = 0; j < 2; ++j) acc[i][j] = f32x4{0.f, 0.f, 0.f, 0.f};

    for (int k0 = 0; k0 < K; k0 += 128) {
#pragma unroll
        for (int i = 0; i < 4; ++i) {
            int g = w * 4 + i;
            int row = g * 4 + lr4;
            int sc = c16 ^ (row & 7);
            GLOAD16(A  + (size_t)(rowBase + row) * K + k0 + sc * 8, &As[g * 512]);
            GLOAD16(Bt + (size_t)(colBase + row) * K + k0 + sc * 8, &Bs[g * 512]);
        }
        __syncthreads();

#pragma unroll
        for (int kk = 0; kk < 4; ++kk) {
            int j = kk * 4 + g4;
            short8 af[2], bfv[2];
#pragma unroll
            for (int f = 0; f < 2; ++f) {
                af[f]  = *(const short8*)&As[lds_idx128(wm + f * 16 + fr, j)];
                bfv[f] = *(const short8*)&Bs[lds_idx128(wn + f * 16 + fr, j)];
            }
#pragma unroll
            for (int fm = 0; fm < 2; ++fm)
#pragma unroll
                for (int fn = 0; fn < 2; ++fn)
                    acc[fm][fn] = __builtin_amdgcn_mfma_f32_16x16x32_bf16(
                        af[fm], bfv[fn], acc[fm][fn], 0, 0, 0);
        }
        __syncthreads();
    }

    const int cr = g4 * 4;
#pragma unroll
    for (int fm = 0; fm < 2; ++fm)
#pragma unroll
        for (int fn = 0; fn < 2; ++fn) {
            int c = colBase + wn + fn * 16 + fr;
            float bv = bias[c];
#pragma unroll
            for (int j = 0; j < 4; ++j) {
                int r = rowBase + wm + fm * 16 + cr + j;
                float v = acc[fm][fn][j] + bv;
                if (EPI == 1) v = 0.5f * v * (1.0f + erff(v * 0.70710678118654752f));
                if (EPI == 2)
                    ((short*)Cv)[(size_t)r * Nn + c] =
                        f2bf(v + bf2f(res[(size_t)r * 256 + c]));
                else
                    ((short*)Cv)[(size_t)r * Nn + c] = f2bf(v);
            }
        }
}

// ---------------------------------------------------------------------------
// ln_kernel: row LayerNorm over 256 cols, one wave per row; bf16 input,
// fp32 output.
// ---------------------------------------------------------------------------
__global__ __launch_bounds__(256) void ln_kernel(
    const short* __restrict__ in, const float* __restrict__ g,
    const float* __restrict__ b, float* __restrict__ out) {
    int wid = blockIdx.x * 4 + (threadIdx.x >> 6);
    int lane = threadIdx.x & 63;

    short4v raw = ((const short4v*)(in + (size_t)wid * 256))[lane];
    float vx = bf2f(raw[0]), vy = bf2f(raw[1]), vz = bf2f(raw[2]), vw = bf2f(raw[3]);
    float s = vx + vy + vz + vw;
#pragma unroll
    for (int off = 32; off; off >>= 1) s += __shfl_xor(s, off);
    float mu = s * (1.0f / 256.0f);
    float dx = vx - mu, dy = vy - mu, dz = vz - mu, dw = vw - mu;
    float ss = dx * dx + dy * dy + dz * dz + dw * dw;
#pragma unroll
    for (int off = 32; off; off >>= 1) ss += __shfl_xor(ss, off);
    float rstd = rsqrtf(ss * (1.0f / 256.0f) + LNEPS);

    float4 gg = ((const float4*)g)[lane];
    float4 bb = ((const float4*)b)[lane];
    float4 o;
    o.x = dx * rstd * gg.x + bb.x;
    o.y = dy * rstd * gg.y + bb.y;
    o.z = dz * rstd * gg.z + bb.z;
    o.w = dw * rstd * gg.w + bb.w;
    ((float4*)(out + (size_t)wid * 256))[lane] = o;
}

// ---------------------------------------------------------------------------
// attnln: fused {segment attention for 16 rows} + {out-proj GEMM, BK=128}
// + {residual + LN1} -> x1 bf16. 384 blocks x 512 threads.
// XCD-chunked block swizzle + bf16 residual (R20-proven).
// ---------------------------------------------------------------------------
__global__ __launch_bounds__(512) void attnln_kernel(
    const short* __restrict__ qkvB, const int* __restrict__ seg_s,
    const int* __restrict__ seg_e, const short* __restrict__ outT,
    const float* __restrict__ out_b, const short* __restrict__ xres,
    const float* __restrict__ gw, const float* __restrict__ bw,
    short* __restrict__ x1) {
    __shared__ __align__(16) short As[16 * 256];    // attn out, swizzled, 8 KB
    __shared__ __align__(16) short Bs[256 * 128];   // 64 KB (BK=128)
    __shared__ float r1[8][16], r2[8][16];

    const int tid = threadIdx.x, lane = tid & 63, w = tid >> 6;
    // XCD-chunked swizzle: 384 blocks, q = 48 per XCD
    const int bid = blockIdx.x;
    const int q = gridDim.x >> 3;
    const int id2 = (bid & 7) * q + (bid >> 3);
    const int rowBase = id2 * 16;
    const int lr4 = lane >> 4, c16 = lane & 15;
    const int fr = lane & 15, g4 = lane >> 4;

    // ---- attention (16 rows x 4 heads = 64 tasks, one per 8-lane group) ----
    {
        const int l8 = lane & 7;
        const int G  = (w << 3) | (lane >> 3);   // 0..63
        int r = G >> 2, h = G & 3;
        int row = rowBase + r;
        short8 qv = *(const short8*)&qkvB[(size_t)row * 768 + h * 64 + l8 * 8];
        float qd[8];
#pragma unroll
        for (int e = 0; e < 8; ++e) qd[e] = bf2f(qv[e]);
        int ss = seg_s[row], ee = seg_e[row];
        float m = -INFINITY, l = 0.0f;
        float acc[8] = {0.f, 0.f, 0.f, 0.f, 0.f, 0.f, 0.f, 0.f};
        for (int j = ss; j < ee; ++j) {
            short8 kv = *(const short8*)&qkvB[(size_t)j * 768 + 256 + h * 64 + l8 * 8];
            short8 vv = *(const short8*)&qkvB[(size_t)j * 768 + 512 + h * 64 + l8 * 8];
            float prod = 0.f;
#pragma unroll
            for (int e = 0; e < 8; ++e) prod += qd[e] * bf2f(kv[e]);
            prod += __shfl_xor(prod, 1);
            prod += __shfl_xor(prod, 2);
            prod += __shfl_xor(prod, 4);
            float score = prod * 0.125f;
            float mn = fmaxf(m, score);
            float scale = __expf(m - mn);
            float p = __expf(score - mn);
            l = l * scale + p;
#pragma unroll
            for (int e = 0; e < 8; ++e) acc[e] = acc[e] * scale + p * bf2f(vv[e]);
            m = mn;
        }
        float inv = 1.0f / l;
        int c = h * 8 + l8;
        short8 o;
#pragma unroll
        for (int e = 0; e < 8; ++e) o[e] = f2bf(acc[e] * inv);
        *(short8*)&As[r * 256 + ((c ^ (r & 7)) * 8)] = o;
    }
    __syncthreads();

    // ---- GEMM (A=attn LDS, B=outT staged BK=128) + residual + LN1 ----
    f32x4 acc[2];
    acc[0] = f32x4{0.f, 0.f, 0.f, 0.f};
    acc[1] = f32x4{0.f, 0.f, 0.f, 0.f};

    for (int k0 = 0; k0 < 256; k0 += 128) {
#pragma unroll
        for (int i = 0; i < 8; ++i) {             // 64 groups of 4 rows
            int g = w * 8 + i;
            int row = g * 4 + lr4;
            int sc = c16 ^ (row & 7);
            GLOAD16(outT + (size_t)row * 256 + k0 + sc * 8, &Bs[g * 512]);
        }
        __syncthreads();
#pragma unroll
        for (int kk = 0; kk < 4; ++kk) {
            int j = kk * 4 + g4;                  // chunk-in-kstep 0..15
            int cj = (k0 >> 3) + j;               // global chunk 0..31
            short8 af = *(const short8*)&As[fr * 256 + ((cj ^ (fr & 7)) * 8)];
            short8 bfv[2];
#pragma unroll
            for (int fn = 0; fn < 2; ++fn)
                bfv[fn] = *(const short8*)&Bs[lds_idx128(w * 32 + fn * 16 + fr, j)];
#pragma unroll
            for (int fn = 0; fn < 2; ++fn)
                acc[fn] = __builtin_amdgcn_mfma_f32_16x16x32_bf16(
                    af, bfv[fn], acc[fn], 0, 0, 0);
        }
        __syncthreads();
    }

    float v[2][4], p1[4], p2[4];
#pragma unroll
    for (int j = 0; j < 4; ++j) { p1[j] = 0.f; p2[j] = 0.f; }
#pragma unroll
    for (int fn = 0; fn < 2; ++fn) {
        int c = w * 32 + fn * 16 + fr;
        float bv = out_b[c];
#pragma unroll
        for (int j = 0; j < 4; ++j) {
            int r = rowBase + g4 * 4 + j;
            float t = acc[fn][j] + bv + bf2f(xres[(size_t)r * 256 + c]);
            v[fn][j] = t;
            p1[j] += t;
            p2[j] += t * t;
        }
    }
#pragma unroll
    for (int m = 1; m < 16; m <<= 1)
#pragma unroll
        for (int j = 0; j < 4; ++j) {
            p1[j] += __shfl_xor(p1[j], m);
            p2[j] += __shfl_xor(p2[j], m);
        }
    if (fr == 0) {
#pragma unroll
        for (int j = 0; j < 4; ++j) {
            r1[w][g4 * 4 + j] = p1[j];
            r2[w][g4 * 4 + j] = p2[j];
        }
    }
    __syncthreads();
#pragma unroll
    for (int j = 0; j < 4; ++j) {
        int rl = g4 * 4 + j;
        int r = rowBase + rl;
        float s1 = 0.f, s2 = 0.f;
#pragma unroll
        for (int ww = 0; ww < 8; ++ww) { s1 += r1[ww][rl]; s2 += r2[ww][rl]; }
        float mu = s1 * (1.0f / 256.0f);
        float var = s2 * (1.0f / 256.0f) - mu * mu;
        float rstd = rsqrtf(var + LNEPS);
#pragma unroll
        for (int fn = 0; fn < 2; ++fn) {
            int c = w * 32 + fn * 16 + fr;
            float o = (v[fn][j] - mu) * rstd * gw[c] + bw[c];
            x1[(size_t)r * 256 + c] = f2bf(o);
        }
    }
}

// ---------------------------------------------------------------------------
extern "C" void kernel_launch(void* const* d_in, const int* in_sizes, int n_in,
                              void* d_out, int out_size, void* d_ws, size_t ws_size,
                              hipStream_t stream) {
    const float* x      = (const float*)d_in[0];
    const int*   dom    = (const int*)d_in[1];
    const float* qkv_w  = (const float*)d_in[2];
    const float* qkv_b  = (const float*)d_in[3];
    const float* out_w  = (const float*)d_in[4];
    const float* out_b  = (const float*)d_in[5];
    const float* ff_w1  = (const float*)d_in[6];
    const float* ff_b1  = (const float*)d_in[7];
    const float* ff_w2  = (const float*)d_in[8];
    const float* ff_b2  = (const float*)d_in[9];
    const float* ln1_g  = (const float*)d_in[10];
    const float* ln1_b  = (const float*)d_in[11];
    const float* ln2_g  = (const float*)d_in[12];
    const float* ln2_b  = (const float*)d_in[13];
    float* out = (float*)d_out;

    short* xB     = (short*)d_ws;                    // NP x 256
    short* qkvB   = xB + (size_t)NP * 256;           // NP x 768
    short* x1     = qkvB + (size_t)NP * 768;         // NP x 256
    short* hB     = x1 + (size_t)NP * 256;           // NP x 1024
    short* qkvT   = hB + (size_t)NP * 1024;          // 768 x 256
    short* outT   = qkvT + 768 * 256;                // 256 x 256
    short* ff1T   = outT + 256 * 256;                // 1024 x 256
    short* ff2T   = ff1T + 1024 * 256;               // 256 x 1024
    int* seg_s    = (int*)(ff2T + 256 * 1024);
    int* seg_e    = seg_s + NP;
    short* yB     = (short*)(seg_e + NP);            // NP x 256 bf16

    // 0) weight transpose/convert + segment bounds + x->bf16
    prep_kernel<<<1560, 256, 0, stream>>>(qkv_w, out_w, ff_w1, ff_w2,
                                          qkvT, outT, ff1T, ff2T,
                                          dom, seg_s, seg_e, x, xB);

    // 1) qkv = x @ qkv_w + qkv_b                (bf16 out, 576 blocks)
    mgemm128x64<0><<<dim3(768 / 64, NP / 128), 256, 0, stream>>>(
        xB, qkvT, qkv_b, qkvB, 768, 256);

    // 2) x1 = LN1(x + attn(qkv) @ out_w + out_b)   (fused, 384 blocks)
    attnln_kernel<<<NP / 16, 512, 0, stream>>>(
        qkvB, seg_s, seg_e, outT, out_b, xB, ln1_g, ln1_b, x1);

    // 3) h = gelu(x1 @ ff_w1 + ff_b1)           (bf16 out, 768 blocks)
    mgemm128x64<1><<<dim3(DFF / 64, NP / 128), 256, 0, stream>>>(
        x1, ff1T, ff_b1, hB, 1024, 256);

    // 4) y = x1 + h @ ff_w2 + ff_b2             (bf16 out, 384 blocks)
    mgemm64<2><<<dim3(DM / 64, NP / 64), 256, 0, stream>>>(
        hB, ff2T, ff_b2, x1, yB, 256, 1024);

    // 5) out = LN2(y)
    ln_kernel<<<NP / 4, 256, 0, stream>>>(yB, ln2_g, ln2_b, out);
}